// Round 1
// 407.648 us; speedup vs baseline: 1.0103x; 1.0103x over previous
//
#include <hip/hip_runtime.h>
#include <hip/hip_fp16.h>

// GridPull: trilinear interpolation, dct2 reflect boundary, extrapolate=True.
// x: (1, 2, 192, 192, 192) f32; grid: (1, 192, 192, 192, 3) f32 voxel coords.
// out: (1, 2, 192, 192, 192) f32.
//
// R4: keep the R3 brick layout (fp16 channel-pairs in 4x2x2-voxel bricks,
// 64B/brick, expected 2.81 lines/sample) but rewrite the repack as an
// LDS-transpose kernel. The old repack issued 32 scattered scalar dword
// loads per thread (0.94 TB/s, ~151 us); the new one does coalesced
// float4 loads -> padded LDS -> contiguous uint4 brick stores
// (141 MB total traffic, should run at streaming BW, ~25 us).

constexpr int DIM = 192;
constexpr int N = DIM * DIM * DIM;       // voxels
constexpr int C = 2;

// brick geometry: 4 voxels along x, 2 along y, 2 along z; 16 voxels * half2 = 64B
constexpr int NBX = DIM / 4;             // 48
constexpr int NBY = DIM / 2;             // 96
constexpr int NBZ = DIM / 2;             // 96
constexpr int NBRICKS = NBX * NBY * NBZ; // 442368
// strides in half2 (=uint32) units
constexpr int XSTRIDE = NBY * NBZ * 16;  // per +4 in ix: 147456
constexpr int YSTRIDE = NBZ * 16;        // per +2 in iy: 1536
constexpr int ZSTRIDE = 16;              // per +2 in iz

typedef float floatx4 __attribute__((ext_vector_type(4)));

__device__ __forceinline__ int reflect_dct2(int i, int n) {
    const int p = 2 * n;
    i = ((i % p) + p) % p;               // nonnegative
    return (i >= n) ? (p - 1 - i) : i;
}

// separable brick-address terms
__device__ __forceinline__ int xterm(int ix) { return (ix >> 2) * XSTRIDE + ((ix & 3) << 2); }
__device__ __forceinline__ int yterm(int iy) { return (iy >> 1) * YSTRIDE + ((iy & 1) << 1); }
__device__ __forceinline__ int zterm(int iz) { return (iz >> 1) * ZSTRIDE + (iz & 1); }

// ---------------------------------------------------------------------------
// Repack via LDS transpose.
// One block per (bx, by) pair: covers ix in [4bx,4bx+4), iy in [2by,2by+2),
// all iz, both channels. Source rows are contiguous in z -> float4 coalesced.
// Destination bricks b = (bx*NBY+by)*NBZ + bz for bz=0..95 are 96*64B
// contiguous -> uint4 coalesced.
// LDS: 16 rows (c,sx,sy) x 192 floats, padded stride 200 so phase-2 reads
// spread uniformly over banks (4 lanes/bank-pair = ds_read_b64 minimum).
// ---------------------------------------------------------------------------
constexpr int LDS_STRIDE = 200;          // floats (192 + 8 pad)

__global__ __launch_bounds__(256) void repack_brick_lds_kernel(
        const float* __restrict__ x,     // (C, N) planar
        uint32_t* __restrict__ xb) {     // bricked half2
    __shared__ float lds[16 * LDS_STRIDE];   // 12.8 KB

    const int bxy = blockIdx.x;          // bx*NBY + by
    const int by  = bxy % NBY;
    const int bx  = bxy / NBY;
    const int tid = threadIdx.x;

    // phase 1: 16 rows x 48 float4 = 768 coalesced vector loads
#pragma unroll
    for (int k = 0; k < 3; ++k) {
        const int vidx = tid + k * 256;  // 0..767
        const int r    = vidx / 48;      // row 0..15 = (c<<3)|(sx<<1)|sy
        const int c4   = vidx - r * 48;  // float4 column within row
        const int c    = r >> 3;
        const int sx   = (r >> 1) & 3;
        const int sy   = r & 1;
        const size_t src = (size_t)c * N
                         + ((size_t)((bx * 4 + sx) * DIM + (by * 2 + sy))) * DIM
                         + (size_t)c4 * 4;
        const floatx4 v = __builtin_nontemporal_load((const floatx4*)(x + src));
        *(floatx4*)(&lds[r * LDS_STRIDE + c4 * 4]) = v;
    }
    __syncthreads();

    // phase 2: 96 bricks * 4 uint4 = 384 contiguous uint4 stores
    for (int slot = tid; slot < NBZ * 4; slot += 256) {
        const int bz = slot >> 2;
        const int q  = slot & 3;         // = sx within brick; uint4 spans s=4q..4q+3
        const int iz = bz * 2;           // even -> float2-aligned LDS reads
        const float2 a00 = *(const float2*)&lds[(((0 << 3) | (q << 1) | 0) * LDS_STRIDE) + iz]; // c0,sy0
        const float2 a01 = *(const float2*)&lds[(((0 << 3) | (q << 1) | 1) * LDS_STRIDE) + iz]; // c0,sy1
        const float2 a10 = *(const float2*)&lds[(((1 << 3) | (q << 1) | 0) * LDS_STRIDE) + iz]; // c1,sy0
        const float2 a11 = *(const float2*)&lds[(((1 << 3) | (q << 1) | 1) * LDS_STRIDE) + iz]; // c1,sy1
        uint4 v;
        v.x = __builtin_bit_cast(uint32_t, __floats2half2_rn(a00.x, a10.x)); // sy0 sz0
        v.y = __builtin_bit_cast(uint32_t, __floats2half2_rn(a00.y, a10.y)); // sy0 sz1
        v.z = __builtin_bit_cast(uint32_t, __floats2half2_rn(a01.x, a11.x)); // sy1 sz0
        v.w = __builtin_bit_cast(uint32_t, __floats2half2_rn(a01.y, a11.y)); // sy1 sz1
        ((uint4*)xb)[(size_t)bxy * (NBZ * 4) + slot] = v;
    }
}

__global__ __launch_bounds__(256) void grid_pull_brick_kernel(
        const uint32_t* __restrict__ xb, // bricked half2
        const float* __restrict__ grid,  // (N, 3)
        float* __restrict__ out) {       // (C, N)
    const int n = blockIdx.x * blockDim.x + threadIdx.x;
    if (n >= N) return;

    const float gx = __builtin_nontemporal_load(&grid[3 * n + 0]);
    const float gy = __builtin_nontemporal_load(&grid[3 * n + 1]);
    const float gz = __builtin_nontemporal_load(&grid[3 * n + 2]);

    const float fx = floorf(gx), fy = floorf(gy), fz = floorf(gz);
    const int lx = (int)fx, ly = (int)fy, lz = (int)fz;
    const float tx = gx - fx, ty = gy - fy, tz = gz - fz;

    const int ix0 = reflect_dct2(lx,     DIM);
    const int ix1 = reflect_dct2(lx + 1, DIM);
    const int iy0 = reflect_dct2(ly,     DIM);
    const int iy1 = reflect_dct2(ly + 1, DIM);
    const int iz0 = reflect_dct2(lz,     DIM);
    const int iz1 = reflect_dct2(lz + 1, DIM);

    const int tx0 = xterm(ix0), tx1 = xterm(ix1);
    const int ty0 = yterm(iy0), ty1 = yterm(iy1);
    const int tz0 = zterm(iz0), tz1 = zterm(iz1);

    const uint32_t u000 = xb[tx0 + ty0 + tz0];
    const uint32_t u001 = xb[tx0 + ty0 + tz1];
    const uint32_t u010 = xb[tx0 + ty1 + tz0];
    const uint32_t u011 = xb[tx0 + ty1 + tz1];
    const uint32_t u100 = xb[tx1 + ty0 + tz0];
    const uint32_t u101 = xb[tx1 + ty0 + tz1];
    const uint32_t u110 = xb[tx1 + ty1 + tz0];
    const uint32_t u111 = xb[tx1 + ty1 + tz1];

    const float wx0 = 1.0f - tx, wx1 = tx;
    const float wy0 = 1.0f - ty, wy1 = ty;
    const float wz0 = 1.0f - tz, wz1 = tz;

    const float w000 = wx0 * wy0 * wz0;
    const float w001 = wx0 * wy0 * wz1;
    const float w010 = wx0 * wy1 * wz0;
    const float w011 = wx0 * wy1 * wz1;
    const float w100 = wx1 * wy0 * wz0;
    const float w101 = wx1 * wy0 * wz1;
    const float w110 = wx1 * wy1 * wz0;
    const float w111 = wx1 * wy1 * wz1;

    const float2 f000 = __half22float2(__builtin_bit_cast(__half2, u000));
    const float2 f001 = __half22float2(__builtin_bit_cast(__half2, u001));
    const float2 f010 = __half22float2(__builtin_bit_cast(__half2, u010));
    const float2 f011 = __half22float2(__builtin_bit_cast(__half2, u011));
    const float2 f100 = __half22float2(__builtin_bit_cast(__half2, u100));
    const float2 f101 = __half22float2(__builtin_bit_cast(__half2, u101));
    const float2 f110 = __half22float2(__builtin_bit_cast(__half2, u110));
    const float2 f111 = __half22float2(__builtin_bit_cast(__half2, u111));

    const float acc0 = f000.x * w000 + f001.x * w001 + f010.x * w010 + f011.x * w011
                     + f100.x * w100 + f101.x * w101 + f110.x * w110 + f111.x * w111;
    const float acc1 = f000.y * w000 + f001.y * w001 + f010.y * w010 + f011.y * w011
                     + f100.y * w100 + f101.y * w101 + f110.y * w110 + f111.y * w111;

    __builtin_nontemporal_store(acc0, &out[n]);
    __builtin_nontemporal_store(acc1, &out[N + n]);
}

// Fallback (R1 kernel) if workspace is too small for the brick array.
__global__ __launch_bounds__(256) void grid_pull_planar_kernel(
        const float* __restrict__ x,
        const float* __restrict__ grid,
        float* __restrict__ out) {
    const int n = blockIdx.x * blockDim.x + threadIdx.x;
    if (n >= N) return;

    const float gx = grid[3 * n + 0];
    const float gy = grid[3 * n + 1];
    const float gz = grid[3 * n + 2];

    const float fx = floorf(gx), fy = floorf(gy), fz = floorf(gz);
    const int lx = (int)fx, ly = (int)fy, lz = (int)fz;
    const float tx = gx - fx, ty = gy - fy, tz = gz - fz;

    const int ix0 = reflect_dct2(lx,     DIM);
    const int ix1 = reflect_dct2(lx + 1, DIM);
    const int iy0 = reflect_dct2(ly,     DIM);
    const int iy1 = reflect_dct2(ly + 1, DIM);
    const int iz0 = reflect_dct2(lz,     DIM);
    const int iz1 = reflect_dct2(lz + 1, DIM);

    const float wx0 = 1.0f - tx, wx1 = tx;
    const float wy0 = 1.0f - ty, wy1 = ty;
    const float wz0 = 1.0f - tz, wz1 = tz;

    const int bx0 = ix0 * (DIM * DIM), bx1 = ix1 * (DIM * DIM);
    const int by0 = iy0 * DIM,         by1 = iy1 * DIM;

    const float w000 = wx0 * wy0 * wz0, w001 = wx0 * wy0 * wz1;
    const float w010 = wx0 * wy1 * wz0, w011 = wx0 * wy1 * wz1;
    const float w100 = wx1 * wy0 * wz0, w101 = wx1 * wy0 * wz1;
    const float w110 = wx1 * wy1 * wz0, w111 = wx1 * wy1 * wz1;

#pragma unroll
    for (int c = 0; c < C; ++c) {
        const float* __restrict__ xc = x + (size_t)c * N;
        float acc = xc[bx0 + by0 + iz0] * w000;
        acc += xc[bx0 + by0 + iz1] * w001;
        acc += xc[bx0 + by1 + iz0] * w010;
        acc += xc[bx0 + by1 + iz1] * w011;
        acc += xc[bx1 + by0 + iz0] * w100;
        acc += xc[bx1 + by0 + iz1] * w101;
        acc += xc[bx1 + by1 + iz0] * w110;
        acc += xc[bx1 + by1 + iz1] * w111;
        out[(size_t)c * N + n] = acc;
    }
}

extern "C" void kernel_launch(void* const* d_in, const int* in_sizes, int n_in,
                              void* d_out, int out_size, void* d_ws, size_t ws_size,
                              hipStream_t stream) {
    const float* x    = (const float*)d_in[0];
    const float* grid = (const float*)d_in[1];
    float* out        = (float*)d_out;

    const int threads = 256;
    const size_t need = (size_t)NBRICKS * 64;   // 28.3 MB

    if (ws_size >= need) {
        uint32_t* xb = (uint32_t*)d_ws;
        repack_brick_lds_kernel<<<NBX * NBY, threads, 0, stream>>>(x, xb);
        const int gblocks = (N + threads - 1) / threads;
        grid_pull_brick_kernel<<<gblocks, threads, 0, stream>>>(xb, grid, out);
    } else {
        const int gblocks = (N + threads - 1) / threads;
        grid_pull_planar_kernel<<<gblocks, threads, 0, stream>>>(x, grid, out);
    }
}

// Round 2
// 338.194 us; speedup vs baseline: 1.2178x; 1.2054x over previous
//
#include <hip/hip_runtime.h>
#include <hip/hip_fp16.h>

// GridPull: trilinear interpolation, dct2 reflect boundary, extrapolate=True.
// x: (1, 2, 192, 192, 192) f32; grid: (1, 192, 192, 192, 3) f32 voxel coords.
// out: (1, 2, 192, 192, 192) f32.
//
// R5: halo'd bricks. R3/R4's 4x2x2 fp16-pair bricks at *aligned* (y,z) give
// E[lines touched per sample] = (1+1/4)(1+1/2)(1+1/2) = 2.81 because the
// 2x2x2 query straddles brick boundaries in y and z half the time. Storing a
// brick at EVERY (y,z) anchor (4x overlap, 113.2 MB — still L3-resident)
// makes y and z never straddle: E[lines] = 1.25, and the 4 corners per x-tap
// become one contiguous dwordx4. reflect_dct2 guarantees |i1-i0| <= 1 per
// axis, so anchor = min(i0,i1) and per-slot weight masses Y0/Y1/Z0/Z1 handle
// boundary duplicate-taps branchlessly.
// Predicted: pull FETCH 908 MB -> ~630 MB, dur 260 -> ~175 us.

constexpr int DIM = 192;
constexpr int N = DIM * DIM * DIM;       // voxels
constexpr int C = 2;

typedef float floatx4 __attribute__((ext_vector_type(4)));

__device__ __forceinline__ int reflect_dct2(int i, int n) {
    const int p = 2 * n;
    i = ((i % p) + p) % p;               // nonnegative
    return (i >= n) ? (p - 1 - i) : i;
}

// ---------------------------------------------------------------------------
// Halo brick layout: brick(bx, y, z), bx in [0,48), y,z in [0,192).
// Brick holds voxels x in [4bx,4bx+4), rows {y, min(y+1,191)}, {z, min(z+1,191)},
// both channels as half2, 16 half2 = 64B per brick.
// Slot s = sx*4 + sy*2 + sz  (sx 0..3, sy/sz 0..1).
// Array: 48*192*192 * 64B = 113,246,208 B.
// ---------------------------------------------------------------------------
constexpr size_t HALO_BRICKS = (size_t)(DIM / 4) * DIM * DIM;   // 1,769,472
constexpr size_t HALO_BYTES  = HALO_BRICKS * 64;                // 113,246,208

constexpr int LDS_STRIDE = 200;          // floats (192 + 8 pad)

// One block per (bx, y): reads 16 source rows (2ch x 4sx x {y,y+1}) of 192
// floats coalesced into LDS, emits 192 bricks (all z anchors) = 768
// contiguous uint4 stores.
__global__ __launch_bounds__(256) void repack_halo_kernel(
        const float* __restrict__ x,     // (C, N) planar
        uint32_t* __restrict__ xb) {     // halo bricks
    __shared__ float lds[16 * LDS_STRIDE];   // 12.8 KB

    const int bxy = blockIdx.x;          // bx*DIM + y
    const int y   = bxy % DIM;
    const int bx  = bxy / DIM;
    const int tid = threadIdx.x;

    // phase 1: 16 rows x 48 float4 = 768 coalesced vector loads
#pragma unroll
    for (int k = 0; k < 3; ++k) {
        const int vidx = tid + k * 256;  // 0..767
        const int r    = vidx / 48;      // row = (c<<3)|(sx<<1)|ysel
        const int c4   = vidx - r * 48;
        const int c    = r >> 3;
        const int sx   = (r >> 1) & 3;
        const int ysel = r & 1;
        const int ysrc = min(y + ysel, DIM - 1);
        const size_t src = (size_t)c * N
                         + ((size_t)((bx * 4 + sx) * DIM + ysrc)) * DIM
                         + (size_t)c4 * 4;
        const floatx4 v = __builtin_nontemporal_load((const floatx4*)(x + src));
        *(floatx4*)(&lds[r * LDS_STRIDE + c4 * 4]) = v;
    }
    __syncthreads();

    // phase 2: 192 bricks (z anchors) * 4 uint4 = 768 contiguous uint4 stores
#pragma unroll
    for (int k = 0; k < 3; ++k) {
        const int t  = tid + k * 256;    // 0..767
        const int z  = t >> 2;
        const int q  = t & 3;            // sx
        const int zp = min(z + 1, DIM - 1);
        const int r00 = q * 2;           // c0, ysel0
        const int r01 = q * 2 + 1;       // c0, ysel1
        const int r10 = 8 + q * 2;       // c1, ysel0
        const int r11 = 8 + q * 2 + 1;   // c1, ysel1
        uint4 v;
        v.x = __builtin_bit_cast(uint32_t,
              __floats2half2_rn(lds[r00 * LDS_STRIDE + z],  lds[r10 * LDS_STRIDE + z]));  // (sy0,sz0)
        v.y = __builtin_bit_cast(uint32_t,
              __floats2half2_rn(lds[r00 * LDS_STRIDE + zp], lds[r10 * LDS_STRIDE + zp])); // (sy0,sz1)
        v.z = __builtin_bit_cast(uint32_t,
              __floats2half2_rn(lds[r01 * LDS_STRIDE + z],  lds[r11 * LDS_STRIDE + z]));  // (sy1,sz0)
        v.w = __builtin_bit_cast(uint32_t,
              __floats2half2_rn(lds[r01 * LDS_STRIDE + zp], lds[r11 * LDS_STRIDE + zp])); // (sy1,sz1)
        ((uint4*)xb)[(size_t)bxy * (DIM * 4) + t] = v;
    }
}

__global__ __launch_bounds__(256) void grid_pull_halo_kernel(
        const uint32_t* __restrict__ xb, // halo bricks
        const float* __restrict__ grid,  // (N, 3)
        float* __restrict__ out) {       // (C, N)
    const int n = blockIdx.x * blockDim.x + threadIdx.x;
    if (n >= N) return;

    const float gx = __builtin_nontemporal_load(&grid[3 * n + 0]);
    const float gy = __builtin_nontemporal_load(&grid[3 * n + 1]);
    const float gz = __builtin_nontemporal_load(&grid[3 * n + 2]);

    const float fx = floorf(gx), fy = floorf(gy), fz = floorf(gz);
    const int lx = (int)fx, ly = (int)fy, lz = (int)fz;
    const float tx = gx - fx, ty = gy - fy, tz = gz - fz;

    const int ix0 = reflect_dct2(lx,     DIM);
    const int ix1 = reflect_dct2(lx + 1, DIM);
    const int iy0 = reflect_dct2(ly,     DIM);
    const int iy1 = reflect_dct2(ly + 1, DIM);
    const int iz0 = reflect_dct2(lz,     DIM);
    const int iz1 = reflect_dct2(lz + 1, DIM);

    // anchors; reflect guarantees |i1-i0| <= 1
    const int ya = min(iy0, iy1), za = min(iz0, iz1);
    const int sy0 = iy0 - ya, sy1 = iy1 - ya;      // each 0/1
    const int sz0 = iz0 - za, sz1 = iz1 - za;

    const float wy0 = 1.0f - ty, wy1 = ty;
    const float wz0 = 1.0f - tz, wz1 = tz;

    // per-slot weight masses (handles duplicate/descending taps at boundary)
    const float Y0 = (sy0 ? 0.0f : wy0) + (sy1 ? 0.0f : wy1);
    const float Y1 = (sy0 ? wy0 : 0.0f) + (sy1 ? wy1 : 0.0f);
    const float Z0 = (sz0 ? 0.0f : wz0) + (sz1 ? 0.0f : wz1);
    const float Z1 = (sz0 ? wz0 : 0.0f) + (sz1 ? wz1 : 0.0f);

    // one dwordx4 per x-tap: 4 contiguous slots (sx<<2)+{00,01,10,11}
    const size_t d0 = ((size_t)(((ix0 >> 2) * DIM + ya) * DIM + za) << 4) + ((ix0 & 3) << 2);
    const size_t d1 = ((size_t)(((ix1 >> 2) * DIM + ya) * DIM + za) << 4) + ((ix1 & 3) << 2);
    const uint4 v0 = *(const uint4*)(xb + d0);
    const uint4 v1 = *(const uint4*)(xb + d1);

    const float2 a00 = __half22float2(__builtin_bit_cast(__half2, v0.x));
    const float2 a01 = __half22float2(__builtin_bit_cast(__half2, v0.y));
    const float2 a10 = __half22float2(__builtin_bit_cast(__half2, v0.z));
    const float2 a11 = __half22float2(__builtin_bit_cast(__half2, v0.w));
    const float2 b00 = __half22float2(__builtin_bit_cast(__half2, v1.x));
    const float2 b01 = __half22float2(__builtin_bit_cast(__half2, v1.y));
    const float2 b10 = __half22float2(__builtin_bit_cast(__half2, v1.z));
    const float2 b11 = __half22float2(__builtin_bit_cast(__half2, v1.w));

    const float wx0 = 1.0f - tx, wx1 = tx;

    const float acc0 = wx0 * (Y0 * (Z0 * a00.x + Z1 * a01.x) + Y1 * (Z0 * a10.x + Z1 * a11.x))
                     + wx1 * (Y0 * (Z0 * b00.x + Z1 * b01.x) + Y1 * (Z0 * b10.x + Z1 * b11.x));
    const float acc1 = wx0 * (Y0 * (Z0 * a00.y + Z1 * a01.y) + Y1 * (Z0 * a10.y + Z1 * a11.y))
                     + wx1 * (Y0 * (Z0 * b00.y + Z1 * b01.y) + Y1 * (Z0 * b10.y + Z1 * b11.y));

    __builtin_nontemporal_store(acc0, &out[n]);
    __builtin_nontemporal_store(acc1, &out[N + n]);
}

// ---------------------------------------------------------------------------
// Fallback 1 (R3/R4): aligned 4x2x2 bricks, 28.3 MB workspace.
// ---------------------------------------------------------------------------
constexpr int NBX = DIM / 4;             // 48
constexpr int NBY = DIM / 2;             // 96
constexpr int NBZ = DIM / 2;             // 96
constexpr int NBRICKS = NBX * NBY * NBZ; // 442368
constexpr int XSTRIDE = NBY * NBZ * 16;
constexpr int YSTRIDE = NBZ * 16;
constexpr int ZSTRIDE = 16;

__device__ __forceinline__ int xterm(int ix) { return (ix >> 2) * XSTRIDE + ((ix & 3) << 2); }
__device__ __forceinline__ int yterm(int iy) { return (iy >> 1) * YSTRIDE + ((iy & 1) << 1); }
__device__ __forceinline__ int zterm(int iz) { return (iz >> 1) * ZSTRIDE + (iz & 1); }

__global__ __launch_bounds__(256) void repack_brick_lds_kernel(
        const float* __restrict__ x,
        uint32_t* __restrict__ xb) {
    __shared__ float lds[16 * LDS_STRIDE];

    const int bxy = blockIdx.x;          // bx*NBY + by
    const int by  = bxy % NBY;
    const int bx  = bxy / NBY;
    const int tid = threadIdx.x;

#pragma unroll
    for (int k = 0; k < 3; ++k) {
        const int vidx = tid + k * 256;
        const int r    = vidx / 48;
        const int c4   = vidx - r * 48;
        const int c    = r >> 3;
        const int sx   = (r >> 1) & 3;
        const int sy   = r & 1;
        const size_t src = (size_t)c * N
                         + ((size_t)((bx * 4 + sx) * DIM + (by * 2 + sy))) * DIM
                         + (size_t)c4 * 4;
        const floatx4 v = __builtin_nontemporal_load((const floatx4*)(x + src));
        *(floatx4*)(&lds[r * LDS_STRIDE + c4 * 4]) = v;
    }
    __syncthreads();

    for (int slot = tid; slot < NBZ * 4; slot += 256) {
        const int bz = slot >> 2;
        const int q  = slot & 3;
        const int iz = bz * 2;
        const float2 a00 = *(const float2*)&lds[(((0 << 3) | (q << 1) | 0) * LDS_STRIDE) + iz];
        const float2 a01 = *(const float2*)&lds[(((0 << 3) | (q << 1) | 1) * LDS_STRIDE) + iz];
        const float2 a10 = *(const float2*)&lds[(((1 << 3) | (q << 1) | 0) * LDS_STRIDE) + iz];
        const float2 a11 = *(const float2*)&lds[(((1 << 3) | (q << 1) | 1) * LDS_STRIDE) + iz];
        uint4 v;
        v.x = __builtin_bit_cast(uint32_t, __floats2half2_rn(a00.x, a10.x));
        v.y = __builtin_bit_cast(uint32_t, __floats2half2_rn(a00.y, a10.y));
        v.z = __builtin_bit_cast(uint32_t, __floats2half2_rn(a01.x, a11.x));
        v.w = __builtin_bit_cast(uint32_t, __floats2half2_rn(a01.y, a11.y));
        ((uint4*)xb)[(size_t)bxy * (NBZ * 4) + slot] = v;
    }
}

__global__ __launch_bounds__(256) void grid_pull_brick_kernel(
        const uint32_t* __restrict__ xb,
        const float* __restrict__ grid,
        float* __restrict__ out) {
    const int n = blockIdx.x * blockDim.x + threadIdx.x;
    if (n >= N) return;

    const float gx = __builtin_nontemporal_load(&grid[3 * n + 0]);
    const float gy = __builtin_nontemporal_load(&grid[3 * n + 1]);
    const float gz = __builtin_nontemporal_load(&grid[3 * n + 2]);

    const float fx = floorf(gx), fy = floorf(gy), fz = floorf(gz);
    const int lx = (int)fx, ly = (int)fy, lz = (int)fz;
    const float tx = gx - fx, ty = gy - fy, tz = gz - fz;

    const int ix0 = reflect_dct2(lx,     DIM);
    const int ix1 = reflect_dct2(lx + 1, DIM);
    const int iy0 = reflect_dct2(ly,     DIM);
    const int iy1 = reflect_dct2(ly + 1, DIM);
    const int iz0 = reflect_dct2(lz,     DIM);
    const int iz1 = reflect_dct2(lz + 1, DIM);

    const int tx0 = xterm(ix0), tx1 = xterm(ix1);
    const int ty0 = yterm(iy0), ty1 = yterm(iy1);
    const int tz0 = zterm(iz0), tz1 = zterm(iz1);

    const uint32_t u000 = xb[tx0 + ty0 + tz0];
    const uint32_t u001 = xb[tx0 + ty0 + tz1];
    const uint32_t u010 = xb[tx0 + ty1 + tz0];
    const uint32_t u011 = xb[tx0 + ty1 + tz1];
    const uint32_t u100 = xb[tx1 + ty0 + tz0];
    const uint32_t u101 = xb[tx1 + ty0 + tz1];
    const uint32_t u110 = xb[tx1 + ty1 + tz0];
    const uint32_t u111 = xb[tx1 + ty1 + tz1];

    const float wx0 = 1.0f - tx, wx1 = tx;
    const float wy0 = 1.0f - ty, wy1 = ty;
    const float wz0 = 1.0f - tz, wz1 = tz;

    const float w000 = wx0 * wy0 * wz0, w001 = wx0 * wy0 * wz1;
    const float w010 = wx0 * wy1 * wz0, w011 = wx0 * wy1 * wz1;
    const float w100 = wx1 * wy0 * wz0, w101 = wx1 * wy0 * wz1;
    const float w110 = wx1 * wy1 * wz0, w111 = wx1 * wy1 * wz1;

    const float2 f000 = __half22float2(__builtin_bit_cast(__half2, u000));
    const float2 f001 = __half22float2(__builtin_bit_cast(__half2, u001));
    const float2 f010 = __half22float2(__builtin_bit_cast(__half2, u010));
    const float2 f011 = __half22float2(__builtin_bit_cast(__half2, u011));
    const float2 f100 = __half22float2(__builtin_bit_cast(__half2, u100));
    const float2 f101 = __half22float2(__builtin_bit_cast(__half2, u101));
    const float2 f110 = __half22float2(__builtin_bit_cast(__half2, u110));
    const float2 f111 = __half22float2(__builtin_bit_cast(__half2, u111));

    const float acc0 = f000.x * w000 + f001.x * w001 + f010.x * w010 + f011.x * w011
                     + f100.x * w100 + f101.x * w101 + f110.x * w110 + f111.x * w111;
    const float acc1 = f000.y * w000 + f001.y * w001 + f010.y * w010 + f011.y * w011
                     + f100.y * w100 + f101.y * w101 + f110.y * w110 + f111.y * w111;

    __builtin_nontemporal_store(acc0, &out[n]);
    __builtin_nontemporal_store(acc1, &out[N + n]);
}

// Fallback 2: no workspace.
__global__ __launch_bounds__(256) void grid_pull_planar_kernel(
        const float* __restrict__ x,
        const float* __restrict__ grid,
        float* __restrict__ out) {
    const int n = blockIdx.x * blockDim.x + threadIdx.x;
    if (n >= N) return;

    const float gx = grid[3 * n + 0];
    const float gy = grid[3 * n + 1];
    const float gz = grid[3 * n + 2];

    const float fx = floorf(gx), fy = floorf(gy), fz = floorf(gz);
    const int lx = (int)fx, ly = (int)fy, lz = (int)fz;
    const float tx = gx - fx, ty = gy - fy, tz = gz - fz;

    const int ix0 = reflect_dct2(lx,     DIM);
    const int ix1 = reflect_dct2(lx + 1, DIM);
    const int iy0 = reflect_dct2(ly,     DIM);
    const int iy1 = reflect_dct2(ly + 1, DIM);
    const int iz0 = reflect_dct2(lz,     DIM);
    const int iz1 = reflect_dct2(lz + 1, DIM);

    const float wx0 = 1.0f - tx, wx1 = tx;
    const float wy0 = 1.0f - ty, wy1 = ty;
    const float wz0 = 1.0f - tz, wz1 = tz;

    const int bx0 = ix0 * (DIM * DIM), bx1 = ix1 * (DIM * DIM);
    const int by0 = iy0 * DIM,         by1 = iy1 * DIM;

    const float w000 = wx0 * wy0 * wz0, w001 = wx0 * wy0 * wz1;
    const float w010 = wx0 * wy1 * wz0, w011 = wx0 * wy1 * wz1;
    const float w100 = wx1 * wy0 * wz0, w101 = wx1 * wy0 * wz1;
    const float w110 = wx1 * wy1 * wz0, w111 = wx1 * wy1 * wz1;

#pragma unroll
    for (int c = 0; c < C; ++c) {
        const float* __restrict__ xc = x + (size_t)c * N;
        float acc = xc[bx0 + by0 + iz0] * w000;
        acc += xc[bx0 + by0 + iz1] * w001;
        acc += xc[bx0 + by1 + iz0] * w010;
        acc += xc[bx0 + by1 + iz1] * w011;
        acc += xc[bx1 + by0 + iz0] * w100;
        acc += xc[bx1 + by0 + iz1] * w101;
        acc += xc[bx1 + by1 + iz0] * w110;
        acc += xc[bx1 + by1 + iz1] * w111;
        out[(size_t)c * N + n] = acc;
    }
}

extern "C" void kernel_launch(void* const* d_in, const int* in_sizes, int n_in,
                              void* d_out, int out_size, void* d_ws, size_t ws_size,
                              hipStream_t stream) {
    const float* x    = (const float*)d_in[0];
    const float* grid = (const float*)d_in[1];
    float* out        = (float*)d_out;

    const int threads = 256;
    const int gblocks = (N + threads - 1) / threads;
    const size_t need_brick = (size_t)NBRICKS * 64;   // 28.3 MB

    if (ws_size >= HALO_BYTES) {
        uint32_t* xb = (uint32_t*)d_ws;
        repack_halo_kernel<<<(DIM / 4) * DIM, threads, 0, stream>>>(x, xb);
        grid_pull_halo_kernel<<<gblocks, threads, 0, stream>>>(xb, grid, out);
    } else if (ws_size >= need_brick) {
        uint32_t* xb = (uint32_t*)d_ws;
        repack_brick_lds_kernel<<<NBX * NBY, threads, 0, stream>>>(x, xb);
        grid_pull_brick_kernel<<<gblocks, threads, 0, stream>>>(xb, grid, out);
    } else {
        grid_pull_planar_kernel<<<gblocks, threads, 0, stream>>>(x, grid, out);
    }
}